// Round 1
// baseline (470.886 us; speedup 1.0000x reference)
//
#include <hip/hip_runtime.h>
#include <stdint.h>

#define NB 16
#define NC 512
#define NHW 4096

typedef unsigned short u16;
typedef __bf16 bf16x8 __attribute__((ext_vector_type(8)));
typedef float f32x4 __attribute__((ext_vector_type(4)));
typedef unsigned short u16x8 __attribute__((ext_vector_type(8)));
typedef unsigned short u16x4 __attribute__((ext_vector_type(4)));

#define AS1 __attribute__((address_space(1)))
#define AS3 __attribute__((address_space(3)))

__device__ __forceinline__ float bf2f(u16 h) {
    union { unsigned u; float f; } a; a.u = ((unsigned)h) << 16; return a.f;
}
__device__ __forceinline__ u16 f2bf(float f) {
    union { float f; unsigned u; } a; a.f = f;
    unsigned u = a.u;
    return (u16)((u + 0x7FFFu + ((u >> 16) & 1u)) >> 16);  // RNE
}

// ---------------- K0: fp32 -> bf16 copy of x ----------------
__global__ __launch_bounds__(256) void k_to_bf16(const float* __restrict__ x,
                                                 u16* __restrict__ xb) {
    int i = blockIdx.x * 256 + threadIdx.x;
    f32x4 v = ((const f32x4*)x)[i];
    u16x4 o;
    o[0] = f2bf(v[0]); o[1] = f2bf(v[1]); o[2] = f2bf(v[2]); o[3] = f2bf(v[3]);
    ((u16x4*)xb)[i] = o;
}

// ---------------- K1: batched C = scale * A * B^T (bf16 in, bf16 out) ------
// A: (128*gridDim.x) x K row-major, B: (128*gridDim.y) x K row-major.
// m97-style: 128x128 tile, BK=32, 256 threads (4 waves, 2x2 of 64x64),
// global_load_lds width-16 staging (flat LDS layout, lane-contiguous).
__global__ __launch_bounds__(256, 2)
void k_gemm_bt(const u16* __restrict__ Ab, const u16* __restrict__ Bb,
               u16* __restrict__ Cb, int K, int N,
               size_t sA, size_t sB, size_t sC, float scale) {
    __shared__ u16 As[128 * 32];  // 8 KB
    __shared__ u16 Bs[128 * 32];  // 8 KB
    const int tid = threadIdx.x;
    const int wave = tid >> 6, lane = tid & 63;
    const int b = blockIdx.z;
    const u16* A  = Ab + (size_t)b * sA + (size_t)blockIdx.x * 128 * K;
    const u16* Bm = Bb + (size_t)b * sB + (size_t)blockIdx.y * 128 * K;

    // staging map: thread t covers row t/4 (+64 on 2nd pass), cols (t%4)*8..+7
    // LDS flat offset = 8*t ushorts -> wave-uniform base + lane*16B  (no padding!)
    const int srow = tid >> 2;
    const int scol = (tid & 3) * 8;
    const u16* ag0 = A  + (size_t)srow * K + scol;
    const u16* ag1 = ag0 + (size_t)64 * K;
    const u16* bg0 = Bm + (size_t)srow * K + scol;
    const u16* bg1 = bg0 + (size_t)64 * K;
    u16* asw0 = &As[wave * 512];
    u16* asw1 = &As[2048 + wave * 512];
    u16* bsw0 = &Bs[wave * 512];
    u16* bsw1 = &Bs[2048 + wave * 512];

    f32x4 acc[4][4];
#pragma unroll
    for (int i = 0; i < 4; i++)
#pragma unroll
        for (int j = 0; j < 4; j++) acc[i][j] = f32x4{0.f, 0.f, 0.f, 0.f};

    const int rm = (wave & 1) * 64;    // wave's m-offset in tile
    const int rn = (wave >> 1) * 64;   // wave's n-offset in tile
    const int m16 = lane & 15, quad = lane >> 4;

    for (int k0 = 0; k0 < K; k0 += 32) {
        __syncthreads();  // prior iter's LDS reads done before overwrite
        __builtin_amdgcn_global_load_lds((AS1 void*)(ag0 + k0), (AS3 void*)asw0, 16, 0, 0);
        __builtin_amdgcn_global_load_lds((AS1 void*)(ag1 + k0), (AS3 void*)asw1, 16, 0, 0);
        __builtin_amdgcn_global_load_lds((AS1 void*)(bg0 + k0), (AS3 void*)bsw0, 16, 0, 0);
        __builtin_amdgcn_global_load_lds((AS1 void*)(bg1 + k0), (AS3 void*)bsw1, 16, 0, 0);
        __syncthreads();  // drains vmcnt(0): staged data visible

        bf16x8 af[4], bfr[4];
#pragma unroll
        for (int mi = 0; mi < 4; mi++)
            af[mi] = *(const bf16x8*)&As[(rm + mi * 16 + m16) * 32 + quad * 8];
#pragma unroll
        for (int ni = 0; ni < 4; ni++)
            bfr[ni] = *(const bf16x8*)&Bs[(rn + ni * 16 + m16) * 32 + quad * 8];
#pragma unroll
        for (int mi = 0; mi < 4; mi++)
#pragma unroll
            for (int ni = 0; ni < 4; ni++)
                acc[mi][ni] = __builtin_amdgcn_mfma_f32_16x16x32_bf16(
                    af[mi], bfr[ni], acc[mi][ni], 0, 0, 0);
    }

    // C/D layout: col = lane&15, row = (lane>>4)*4 + reg  (m89-verified)
    u16* Co = Cb + (size_t)b * sC + ((size_t)blockIdx.x * 128) * N + blockIdx.y * 128;
    const int rq = quad * 4;
#pragma unroll
    for (int mi = 0; mi < 4; mi++)
#pragma unroll
        for (int ni = 0; ni < 4; ni++)
#pragma unroll
            for (int r = 0; r < 4; r++) {
                int row = rm + mi * 16 + rq + r;
                int col = rn + ni * 16 + m16;
                Co[(size_t)row * N + col] = f2bf(acc[mi][ni][r] * scale);
            }
}

// ---------------- K2: power iteration (one block per batch) ----------------
// v10 dir = (S2)^5 v0 = S^10 v0 (intermediate norms are pure scaling; S=Ws/4096
// keeps magnitudes safe). s^2 = ||X^T vhat||^2 = 4096 * v10'S v10 / ||v10||^2.
__device__ __forceinline__ float block_sum(float x, float* red, int tid) {
#pragma unroll
    for (int o = 32; o > 0; o >>= 1) x += __shfl_down(x, o, 64);
    __syncthreads();
    if ((tid & 63) == 0) red[tid >> 6] = x;
    __syncthreads();
    float s = red[0];
#pragma unroll
    for (int w = 1; w < 8; w++) s += red[w];
    return s;
}

__global__ __launch_bounds__(512, 1)
void k_power_iter(const u16* __restrict__ S, const u16* __restrict__ S2,
                  const float* __restrict__ v0, float* __restrict__ vhat,
                  float* __restrict__ coef) {
    const int b = blockIdx.x, tid = threadIdx.x;
    __shared__ float va[NC], vb[NC];
    __shared__ float red[16];
    const u16* Sb  = S  + (size_t)b * NC * NC;
    const u16* S2b = S2 + (size_t)b * NC * NC;
    va[tid] = v0[b * NC + tid];
    __syncthreads();
    float* cur = va;
    float* nxt = vb;
    for (int it = 0; it < 5; ++it) {
        const u16* row = S2b + (size_t)tid * NC;
        float acc = 0.f;
        for (int k = 0; k < NC; k += 8) {
            u16x8 w = *(const u16x8*)(row + k);
#pragma unroll
            for (int j = 0; j < 8; j++) acc += bf2f(w[j]) * cur[k + j];
        }
        nxt[tid] = acc;
        __syncthreads();
        float* t = cur; cur = nxt; nxt = t;
    }
    // cur = v10 (unnormalized). One S-matvec for the u-norm.
    const u16* row = Sb + (size_t)tid * NC;
    float r = 0.f;
    for (int k = 0; k < NC; k += 8) {
        u16x8 w = *(const u16x8*)(row + k);
#pragma unroll
        for (int j = 0; j < 8; j++) r += bf2f(w[j]) * cur[k + j];
    }
    float myv = cur[tid];
    float n10 = block_sum(myv * myv, red, tid);
    float d   = block_sum(myv * r, red, tid);
    float inv = rsqrtf(n10);
    float s   = sqrtf(4096.f * d / n10);   // ||X^T vhat||
    float vh  = myv * inv;
    vhat[b * NC + tid] = vh;
    coef[b * NC + tid] = vh / s;
}

// ---------------- K3: t[n] = sum_c xb[b][c][n] * vhat[b][c]  (c-split x4) ---
__global__ __launch_bounds__(256)
void k_compute_t(const u16* __restrict__ xb, const float* __restrict__ vhat,
                 float* __restrict__ tp) {
    const int b = blockIdx.z, cc = blockIdx.y, nc = blockIdx.x, tid = threadIdx.x;
    __shared__ float vsh[128];
    if (tid < 128) vsh[tid] = vhat[b * NC + cc * 128 + tid];
    __syncthreads();
    const int n0 = nc * 2048 + tid * 8;
    const u16* xp = xb + (size_t)b * NC * NHW + (size_t)cc * 128 * NHW + n0;
    float acc[8] = {0.f, 0.f, 0.f, 0.f, 0.f, 0.f, 0.f, 0.f};
    for (int c = 0; c < 128; c++) {
        u16x8 w = *(const u16x8*)xp;
        xp += NHW;
        float vc = vsh[c];
#pragma unroll
        for (int j = 0; j < 8; j++) acc[j] += bf2f(w[j]) * vc;
    }
    float* dst = tp + (size_t)(b * 4 + cc) * NHW + n0;
    *(f32x4*)dst       = f32x4{acc[0], acc[1], acc[2], acc[3]};
    *(f32x4*)(dst + 4) = f32x4{acc[4], acc[5], acc[6], acc[7]};
}

// ---------------- K4: out = x + t[n] * coef[c] ----------------
__global__ __launch_bounds__(256)
void k_epilogue(const float* __restrict__ x, const float* __restrict__ tp,
                const float* __restrict__ coef, float* __restrict__ out) {
    const int b = blockIdx.z, cc = blockIdx.y, nc = blockIdx.x, tid = threadIdx.x;
    __shared__ float tl[1024];
    __shared__ float cf[64];
    const int nbase = nc * 1024, cbase = cc * 64;
    for (int i = tid; i < 1024; i += 256) {
        float s = 0.f;
#pragma unroll
        for (int p = 0; p < 4; p++) s += tp[(size_t)(b * 4 + p) * NHW + nbase + i];
        tl[i] = s;
    }
    if (tid < 64) cf[tid] = coef[b * NC + cbase + tid];
    __syncthreads();
    f32x4 tv = ((const f32x4*)tl)[tid];
    for (int rr = 0; rr < 64; rr++) {
        size_t off = ((size_t)(b * NC + cbase + rr)) * NHW + nbase + tid * 4;
        f32x4 xv = *(const f32x4*)(x + off);
        float c = cf[rr];
        f32x4 o = xv + tv * c;
        *(f32x4*)(out + off) = o;
    }
}

extern "C" void kernel_launch(void* const* d_in, const int* in_sizes, int n_in,
                              void* d_out, int out_size, void* d_ws, size_t ws_size,
                              hipStream_t stream) {
    const float* x  = (const float*)d_in[0];   // (16,512,64,64) fp32
    const float* v0 = (const float*)d_in[1];   // (16,512,1) fp32
    float* out = (float*)d_out;

    char* ws = (char*)d_ws;
    u16* xb    = (u16*)ws;                                    // 64 MiB bf16 x
    u16* S     = (u16*)(ws + 67108864);                       // 8 MiB  Ws/4096
    u16* S2    = (u16*)(ws + 67108864 + 8388608);             // 8 MiB  S^2
    float* vhat = (float*)(ws + 83886080);                    // 32 KiB
    float* coef = (float*)(ws + 83886080 + 32768);            // 32 KiB
    float* tp   = (float*)(ws + 83886080 + 65536);            // 1 MiB (4 c-partials)

    k_to_bf16<<<dim3(32768), dim3(256), 0, stream>>>(x, xb);
    // S = (X X^T) / 4096   (M=N=512, K=4096; B operand == A -> symmetric, safe)
    k_gemm_bt<<<dim3(4, 4, NB), dim3(256), 0, stream>>>(
        xb, xb, S, NHW, NC, (size_t)NC * NHW, (size_t)NC * NHW, (size_t)NC * NC,
        1.f / 4096.f);
    // S2 = S * S^T = S * S   (M=N=K=512)
    k_gemm_bt<<<dim3(4, 4, NB), dim3(256), 0, stream>>>(
        S, S, S2, NC, NC, (size_t)NC * NC, (size_t)NC * NC, (size_t)NC * NC, 1.f);
    k_power_iter<<<dim3(NB), dim3(512), 0, stream>>>(S, S2, v0, vhat, coef);
    k_compute_t<<<dim3(2, 4, NB), dim3(256), 0, stream>>>(xb, vhat, tp);
    k_epilogue<<<dim3(4, 8, NB), dim3(256), 0, stream>>>(x, tp, coef, out);
}

// Round 2
// 457.031 us; speedup vs baseline: 1.0303x; 1.0303x over previous
//
#include <hip/hip_runtime.h>
#include <stdint.h>

#define NB 16
#define NC 512
#define NHW 4096

typedef unsigned short u16;
typedef __bf16 bf16x8 __attribute__((ext_vector_type(8)));
typedef float f32x4 __attribute__((ext_vector_type(4)));
typedef unsigned short u16x8 __attribute__((ext_vector_type(8)));
typedef unsigned short u16x4 __attribute__((ext_vector_type(4)));

#define AS1 __attribute__((address_space(1)))
#define AS3 __attribute__((address_space(3)))

__device__ __forceinline__ float bf2f(u16 h) {
    union { unsigned u; float f; } a; a.u = ((unsigned)h) << 16; return a.f;
}
__device__ __forceinline__ u16 f2bf(float f) {
    union { float f; unsigned u; } a; a.f = f;
    unsigned u = a.u;
    return (u16)((u + 0x7FFFu + ((u >> 16) & 1u)) >> 16);  // RNE
}

// ---------------- K0: fp32 -> bf16 copy of x ----------------
__global__ __launch_bounds__(256) void k_to_bf16(const float* __restrict__ x,
                                                 u16* __restrict__ xb) {
    int i = blockIdx.x * 256 + threadIdx.x;
    f32x4 v = ((const f32x4*)x)[i];
    u16x4 o;
    o[0] = f2bf(v[0]); o[1] = f2bf(v[1]); o[2] = f2bf(v[2]); o[3] = f2bf(v[3]);
    ((u16x4*)xb)[i] = o;
}

// ---------------- K1: batched C = scale * A * B^T (bf16 in, bf16 out) ------
// m97-style: 128x128 tile, BK=32, 256 threads (4 waves, 2x2 of 64x64),
// global_load_lds width-16 staging (flat LDS layout, lane-contiguous).
__global__ __launch_bounds__(256, 2)
void k_gemm_bt(const u16* __restrict__ Ab, const u16* __restrict__ Bb,
               u16* __restrict__ Cb, int K, int N,
               size_t sA, size_t sB, size_t sC, float scale) {
    __shared__ u16 As[128 * 32];  // 8 KB
    __shared__ u16 Bs[128 * 32];  // 8 KB
    const int tid = threadIdx.x;
    const int wave = tid >> 6, lane = tid & 63;
    const int b = blockIdx.z;
    const u16* A  = Ab + (size_t)b * sA + (size_t)blockIdx.x * 128 * K;
    const u16* Bm = Bb + (size_t)b * sB + (size_t)blockIdx.y * 128 * K;

    const int srow = tid >> 2;
    const int scol = (tid & 3) * 8;
    const u16* ag0 = A  + (size_t)srow * K + scol;
    const u16* ag1 = ag0 + (size_t)64 * K;
    const u16* bg0 = Bm + (size_t)srow * K + scol;
    const u16* bg1 = bg0 + (size_t)64 * K;
    u16* asw0 = &As[wave * 512];
    u16* asw1 = &As[2048 + wave * 512];
    u16* bsw0 = &Bs[wave * 512];
    u16* bsw1 = &Bs[2048 + wave * 512];

    f32x4 acc[4][4];
#pragma unroll
    for (int i = 0; i < 4; i++)
#pragma unroll
        for (int j = 0; j < 4; j++) acc[i][j] = f32x4{0.f, 0.f, 0.f, 0.f};

    const int rm = (wave & 1) * 64;
    const int rn = (wave >> 1) * 64;
    const int m16 = lane & 15, quad = lane >> 4;

    for (int k0 = 0; k0 < K; k0 += 32) {
        __syncthreads();
        __builtin_amdgcn_global_load_lds((AS1 void*)(ag0 + k0), (AS3 void*)asw0, 16, 0, 0);
        __builtin_amdgcn_global_load_lds((AS1 void*)(ag1 + k0), (AS3 void*)asw1, 16, 0, 0);
        __builtin_amdgcn_global_load_lds((AS1 void*)(bg0 + k0), (AS3 void*)bsw0, 16, 0, 0);
        __builtin_amdgcn_global_load_lds((AS1 void*)(bg1 + k0), (AS3 void*)bsw1, 16, 0, 0);
        __syncthreads();

        bf16x8 af[4], bfr[4];
#pragma unroll
        for (int mi = 0; mi < 4; mi++)
            af[mi] = *(const bf16x8*)&As[(rm + mi * 16 + m16) * 32 + quad * 8];
#pragma unroll
        for (int ni = 0; ni < 4; ni++)
            bfr[ni] = *(const bf16x8*)&Bs[(rn + ni * 16 + m16) * 32 + quad * 8];
#pragma unroll
        for (int mi = 0; mi < 4; mi++)
#pragma unroll
            for (int ni = 0; ni < 4; ni++)
                acc[mi][ni] = __builtin_amdgcn_mfma_f32_16x16x32_bf16(
                    af[mi], bfr[ni], acc[mi][ni], 0, 0, 0);
    }

    // C/D layout: col = lane&15, row = (lane>>4)*4 + reg  (m89-verified)
    u16* Co = Cb + (size_t)b * sC + ((size_t)blockIdx.x * 128) * N + blockIdx.y * 128;
    const int rq = quad * 4;
#pragma unroll
    for (int mi = 0; mi < 4; mi++)
#pragma unroll
        for (int ni = 0; ni < 4; ni++)
#pragma unroll
            for (int r = 0; r < 4; r++) {
                int row = rm + mi * 16 + rq + r;
                int col = rn + ni * 16 + m16;
                Co[(size_t)row * N + col] = f2bf(acc[mi][ni][r] * scale);
            }
}

// ---------------- K2: power iteration (one block per batch) ----------------
// v10 dir = (S2)^5 v0 = S^10 v0 (normalization is pure scaling; S=Ws/4096).
// s^2 = ||X^T vhat||^2 = 4096 * (v10' S v10) / ||v10||^2.
// Matvec: one row per wave-iteration — 64 lanes read the full 1KB row
// coalesced (u16x8/lane), 8 FMA vs register-resident cur-slice, shfl reduce.
__device__ __forceinline__ float block_sum16(float x, float* red, int tid) {
#pragma unroll
    for (int o = 32; o > 0; o >>= 1) x += __shfl_down(x, o, 64);
    if ((tid & 63) == 0) red[tid >> 6] = x;
    __syncthreads();
    float s = red[0];
#pragma unroll
    for (int w = 1; w < 16; w++) s += red[w];
    __syncthreads();  // allow red reuse
    return s;
}

__global__ __launch_bounds__(1024, 1)
void k_power_iter(const u16* __restrict__ S, const u16* __restrict__ S2,
                  const float* __restrict__ v0, float* __restrict__ vhat,
                  float* __restrict__ coef) {
    const int b = blockIdx.x, tid = threadIdx.x;
    const int wave = tid >> 6, lane = tid & 63;
    __shared__ float va[NC], vb[NC];
    __shared__ float red[16];
    const u16* Sb  = S  + (size_t)b * NC * NC;
    const u16* S2b = S2 + (size_t)b * NC * NC;
    if (tid < NC) va[tid] = v0[b * NC + tid];
    __syncthreads();
    float* cur = va;
    float* nxt = vb;

    const int row0 = wave * 32;  // 16 waves x 32 rows = 512
    for (int it = 0; it < 5; ++it) {
        // hoist lane's slice of cur into registers
        float c[8];
#pragma unroll
        for (int j = 0; j < 8; j++) c[j] = cur[lane * 8 + j];
        const u16* M0 = S2b + (size_t)row0 * NC + lane * 8;
#pragma unroll 4
        for (int rr = 0; rr < 32; ++rr) {
            u16x8 m = *(const u16x8*)(M0 + (size_t)rr * NC);
            float d0 = bf2f(m[0]) * c[0] + bf2f(m[1]) * c[1];
            float d1 = bf2f(m[2]) * c[2] + bf2f(m[3]) * c[3];
            float d2 = bf2f(m[4]) * c[4] + bf2f(m[5]) * c[5];
            float d3 = bf2f(m[6]) * c[6] + bf2f(m[7]) * c[7];
            float d = (d0 + d1) + (d2 + d3);
#pragma unroll
            for (int o = 32; o > 0; o >>= 1) d += __shfl_down(d, o, 64);
            if (lane == 0) nxt[row0 + rr] = d;
        }
        __syncthreads();
        float* t = cur; cur = nxt; nxt = t;
    }
    // cur = v10 (unnormalized). One S-matvec for the u-norm (into nxt, no swap).
    {
        float c[8];
#pragma unroll
        for (int j = 0; j < 8; j++) c[j] = cur[lane * 8 + j];
        const u16* M0 = Sb + (size_t)row0 * NC + lane * 8;
#pragma unroll 4
        for (int rr = 0; rr < 32; ++rr) {
            u16x8 m = *(const u16x8*)(M0 + (size_t)rr * NC);
            float d0 = bf2f(m[0]) * c[0] + bf2f(m[1]) * c[1];
            float d1 = bf2f(m[2]) * c[2] + bf2f(m[3]) * c[3];
            float d2 = bf2f(m[4]) * c[4] + bf2f(m[5]) * c[5];
            float d3 = bf2f(m[6]) * c[6] + bf2f(m[7]) * c[7];
            float d = (d0 + d1) + (d2 + d3);
#pragma unroll
            for (int o = 32; o > 0; o >>= 1) d += __shfl_down(d, o, 64);
            if (lane == 0) nxt[row0 + rr] = d;
        }
        __syncthreads();
    }
    float myv = (tid < NC) ? cur[tid] : 0.f;
    float myr = (tid < NC) ? nxt[tid] : 0.f;
    float n10 = block_sum16(myv * myv, red, tid);
    float d   = block_sum16(myv * myr, red, tid);
    float inv = rsqrtf(n10);
    float s   = sqrtf(4096.f * d / n10);   // ||X^T vhat||
    if (tid < NC) {
        float vh = myv * inv;
        vhat[b * NC + tid] = vh;
        coef[b * NC + tid] = vh / s;
    }
}

// ---------------- K3: t[n] = sum_c xb[b][c][n] * vhat[b][c]  (c-split x4) ---
__global__ __launch_bounds__(256)
void k_compute_t(const u16* __restrict__ xb, const float* __restrict__ vhat,
                 float* __restrict__ tp) {
    const int b = blockIdx.z, cc = blockIdx.y, nc = blockIdx.x, tid = threadIdx.x;
    __shared__ float vsh[128];
    if (tid < 128) vsh[tid] = vhat[b * NC + cc * 128 + tid];
    __syncthreads();
    const int n0 = nc * 2048 + tid * 8;
    const u16* xp = xb + (size_t)b * NC * NHW + (size_t)cc * 128 * NHW + n0;
    float acc[8] = {0.f, 0.f, 0.f, 0.f, 0.f, 0.f, 0.f, 0.f};
    for (int c = 0; c < 128; c++) {
        u16x8 w = *(const u16x8*)xp;
        xp += NHW;
        float vc = vsh[c];
#pragma unroll
        for (int j = 0; j < 8; j++) acc[j] += bf2f(w[j]) * vc;
    }
    float* dst = tp + (size_t)(b * 4 + cc) * NHW + n0;
    *(f32x4*)dst       = f32x4{acc[0], acc[1], acc[2], acc[3]};
    *(f32x4*)(dst + 4) = f32x4{acc[4], acc[5], acc[6], acc[7]};
}

// ---------------- K4: out = x + t[n] * coef[c] ----------------
__global__ __launch_bounds__(256)
void k_epilogue(const float* __restrict__ x, const float* __restrict__ tp,
                const float* __restrict__ coef, float* __restrict__ out) {
    const int b = blockIdx.z, cc = blockIdx.y, nc = blockIdx.x, tid = threadIdx.x;
    __shared__ float tl[1024];
    __shared__ float cf[64];
    const int nbase = nc * 1024, cbase = cc * 64;
    for (int i = tid; i < 1024; i += 256) {
        float s = 0.f;
#pragma unroll
        for (int p = 0; p < 4; p++) s += tp[(size_t)(b * 4 + p) * NHW + nbase + i];
        tl[i] = s;
    }
    if (tid < 64) cf[tid] = coef[b * NC + cbase + tid];
    __syncthreads();
    f32x4 tv = ((const f32x4*)tl)[tid];
    for (int rr = 0; rr < 64; rr++) {
        size_t off = ((size_t)(b * NC + cbase + rr)) * NHW + nbase + tid * 4;
        f32x4 xv = *(const f32x4*)(x + off);
        float c = cf[rr];
        f32x4 o = xv + tv * c;
        *(f32x4*)(out + off) = o;
    }
}

extern "C" void kernel_launch(void* const* d_in, const int* in_sizes, int n_in,
                              void* d_out, int out_size, void* d_ws, size_t ws_size,
                              hipStream_t stream) {
    const float* x  = (const float*)d_in[0];   // (16,512,64,64) fp32
    const float* v0 = (const float*)d_in[1];   // (16,512,1) fp32
    float* out = (float*)d_out;

    char* ws = (char*)d_ws;
    u16* xb    = (u16*)ws;                                    // 64 MiB bf16 x
    u16* S     = (u16*)(ws + 67108864);                       // 8 MiB  Ws/4096
    u16* S2    = (u16*)(ws + 67108864 + 8388608);             // 8 MiB  S^2
    float* vhat = (float*)(ws + 83886080);                    // 32 KiB
    float* coef = (float*)(ws + 83886080 + 32768);            // 32 KiB
    float* tp   = (float*)(ws + 83886080 + 65536);            // 1 MiB (4 c-partials)

    k_to_bf16<<<dim3(32768), dim3(256), 0, stream>>>(x, xb);
    // S = (X X^T) / 4096   (M=N=512, K=4096)
    k_gemm_bt<<<dim3(4, 4, NB), dim3(256), 0, stream>>>(
        xb, xb, S, NHW, NC, (size_t)NC * NHW, (size_t)NC * NHW, (size_t)NC * NC,
        1.f / 4096.f);
    // S2 = S * S^T = S * S   (M=N=K=512, S symmetric)
    k_gemm_bt<<<dim3(4, 4, NB), dim3(256), 0, stream>>>(
        S, S, S2, NC, NC, (size_t)NC * NC, (size_t)NC * NC, (size_t)NC * NC, 1.f);
    k_power_iter<<<dim3(NB), dim3(1024), 0, stream>>>(S, S2, v0, vhat, coef);
    k_compute_t<<<dim3(2, 4, NB), dim3(256), 0, stream>>>(xb, vhat, tp);
    k_epilogue<<<dim3(4, 8, NB), dim3(256), 0, stream>>>(x, tp, coef, out);
}

// Round 3
// 400.550 us; speedup vs baseline: 1.1756x; 1.1410x over previous
//
#include <hip/hip_runtime.h>
#include <stdint.h>

#define NB 16
#define NC 512
#define NHW 4096

typedef unsigned short u16;
typedef __bf16 bf16x8 __attribute__((ext_vector_type(8)));
typedef float f32x4 __attribute__((ext_vector_type(4)));
typedef unsigned short u16x8 __attribute__((ext_vector_type(8)));
typedef unsigned short u16x4 __attribute__((ext_vector_type(4)));

#define AS1 __attribute__((address_space(1)))
#define AS3 __attribute__((address_space(3)))

__device__ __forceinline__ float bf2f(u16 h) {
    union { unsigned u; float f; } a; a.u = ((unsigned)h) << 16; return a.f;
}
__device__ __forceinline__ u16 f2bf(float f) {
    union { float f; unsigned u; } a; a.f = f;
    unsigned u = a.u;
    return (u16)((u + 0x7FFFu + ((u >> 16) & 1u)) >> 16);  // RNE
}

// ---------------- K0: fp32 -> bf16 copy of x ----------------
__global__ __launch_bounds__(256) void k_to_bf16(const float* __restrict__ x,
                                                 u16* __restrict__ xb) {
    int i = blockIdx.x * 256 + threadIdx.x;
    f32x4 v = ((const f32x4*)x)[i];
    u16x4 o;
    o[0] = f2bf(v[0]); o[1] = f2bf(v[1]); o[2] = f2bf(v[2]); o[3] = f2bf(v[3]);
    ((u16x4*)xb)[i] = o;
}

// ---------------- K1: batched C = scale * A * B^T (bf16 in, bf16 out) ------
// m97-style: 128x128 tile, BK=32, 256 threads (4 waves, 2x2 of 64x64),
// global_load_lds width-16 staging (flat LDS layout, lane-contiguous).
__global__ __launch_bounds__(256, 2)
void k_gemm_bt(const u16* __restrict__ Ab, const u16* __restrict__ Bb,
               u16* __restrict__ Cb, int K, int N,
               size_t sA, size_t sB, size_t sC, float scale) {
    __shared__ u16 As[128 * 32];  // 8 KB
    __shared__ u16 Bs[128 * 32];  // 8 KB
    const int tid = threadIdx.x;
    const int wave = tid >> 6, lane = tid & 63;
    const int b = blockIdx.z;
    const u16* A  = Ab + (size_t)b * sA + (size_t)blockIdx.x * 128 * K;
    const u16* Bm = Bb + (size_t)b * sB + (size_t)blockIdx.y * 128 * K;

    const int srow = tid >> 2;
    const int scol = (tid & 3) * 8;
    const u16* ag0 = A  + (size_t)srow * K + scol;
    const u16* ag1 = ag0 + (size_t)64 * K;
    const u16* bg0 = Bm + (size_t)srow * K + scol;
    const u16* bg1 = bg0 + (size_t)64 * K;
    u16* asw0 = &As[wave * 512];
    u16* asw1 = &As[2048 + wave * 512];
    u16* bsw0 = &Bs[wave * 512];
    u16* bsw1 = &Bs[2048 + wave * 512];

    f32x4 acc[4][4];
#pragma unroll
    for (int i = 0; i < 4; i++)
#pragma unroll
        for (int j = 0; j < 4; j++) acc[i][j] = f32x4{0.f, 0.f, 0.f, 0.f};

    const int rm = (wave & 1) * 64;
    const int rn = (wave >> 1) * 64;
    const int m16 = lane & 15, quad = lane >> 4;

    for (int k0 = 0; k0 < K; k0 += 32) {
        __syncthreads();
        __builtin_amdgcn_global_load_lds((AS1 void*)(ag0 + k0), (AS3 void*)asw0, 16, 0, 0);
        __builtin_amdgcn_global_load_lds((AS1 void*)(ag1 + k0), (AS3 void*)asw1, 16, 0, 0);
        __builtin_amdgcn_global_load_lds((AS1 void*)(bg0 + k0), (AS3 void*)bsw0, 16, 0, 0);
        __builtin_amdgcn_global_load_lds((AS1 void*)(bg1 + k0), (AS3 void*)bsw1, 16, 0, 0);
        __syncthreads();

        bf16x8 af[4], bfr[4];
#pragma unroll
        for (int mi = 0; mi < 4; mi++)
            af[mi] = *(const bf16x8*)&As[(rm + mi * 16 + m16) * 32 + quad * 8];
#pragma unroll
        for (int ni = 0; ni < 4; ni++)
            bfr[ni] = *(const bf16x8*)&Bs[(rn + ni * 16 + m16) * 32 + quad * 8];
#pragma unroll
        for (int mi = 0; mi < 4; mi++)
#pragma unroll
            for (int ni = 0; ni < 4; ni++)
                acc[mi][ni] = __builtin_amdgcn_mfma_f32_16x16x32_bf16(
                    af[mi], bfr[ni], acc[mi][ni], 0, 0, 0);
    }

    // C/D layout: col = lane&15, row = (lane>>4)*4 + reg  (m89-verified)
    u16* Co = Cb + (size_t)b * sC + ((size_t)blockIdx.x * 128) * N + blockIdx.y * 128;
    const int rq = quad * 4;
#pragma unroll
    for (int mi = 0; mi < 4; mi++)
#pragma unroll
        for (int ni = 0; ni < 4; ni++)
#pragma unroll
            for (int r = 0; r < 4; r++) {
                int row = rm + mi * 16 + rq + r;
                int col = rn + ni * 16 + m16;
                Co[(size_t)row * N + col] = f2bf(acc[mi][ni][r] * scale);
            }
}

// ---------------- K2: power iteration (one block per batch) ----------------
// vhat dir = (S2)^5 v0 = S^10 v0 (normalization is pure scaling; S=Ws/4096).
// Matvec layout: thread = (row r, col-group cg of 32 cols). 4 independent
// u16x8 loads + 64 VALU per pass, NO shuffles; partials via LDS part[r][cg],
// flat 16-wide reduction. 8 passes x 64 rows = 512 rows.
__global__ __launch_bounds__(1024, 1)
void k_power_iter(const u16* __restrict__ S2, const float* __restrict__ v0,
                  float* __restrict__ vhat) {
    const int b = blockIdx.x, tid = threadIdx.x;
    __shared__ float va[NC], vb[NC];
    __shared__ float part[NC][16];   // 32 KB
    __shared__ float red[16];
    const u16* Mb = S2 + (size_t)b * NC * NC;
    const int cg = tid & 15;   // col group: cols cg*8 + p*128 + j (p=0..3)
    const int r0 = tid >> 4;   // row-in-pass (0..63)
    if (tid < NC) va[tid] = v0[b * NC + tid];
    float* cur = va;
    float* nxt = vb;
    __syncthreads();

    for (int it = 0; it < 5; ++it) {
        // hoist this thread's 32 cur values (vectorizes to ds_read_b128 x8)
        float c[4][8];
#pragma unroll
        for (int p = 0; p < 4; p++) {
            f32x4 lo = *(const f32x4*)&cur[cg * 8 + p * 128];
            f32x4 hi = *(const f32x4*)&cur[cg * 8 + p * 128 + 4];
            c[p][0] = lo[0]; c[p][1] = lo[1]; c[p][2] = lo[2]; c[p][3] = lo[3];
            c[p][4] = hi[0]; c[p][5] = hi[1]; c[p][6] = hi[2]; c[p][7] = hi[3];
        }
#pragma unroll 2
        for (int pass = 0; pass < 8; ++pass) {
            const int r = pass * 64 + r0;
            const u16* row = Mb + (size_t)r * NC + cg * 8;
            u16x8 m[4];
#pragma unroll
            for (int p = 0; p < 4; p++) m[p] = *(const u16x8*)(row + p * 128);
            float a0 = 0.f, a1 = 0.f, a2 = 0.f, a3 = 0.f;
#pragma unroll
            for (int j = 0; j < 8; j++) {
                a0 += bf2f(m[0][j]) * c[0][j];
                a1 += bf2f(m[1][j]) * c[1][j];
                a2 += bf2f(m[2][j]) * c[2][j];
                a3 += bf2f(m[3][j]) * c[3][j];
            }
            part[r][cg] = (a0 + a1) + (a2 + a3);
        }
        __syncthreads();
        if (tid < NC) {
            f32x4 s0 = *(const f32x4*)&part[tid][0];
            f32x4 s1 = *(const f32x4*)&part[tid][4];
            f32x4 s2 = *(const f32x4*)&part[tid][8];
            f32x4 s3 = *(const f32x4*)&part[tid][12];
            f32x4 s = (s0 + s1) + (s2 + s3);
            nxt[tid] = (s[0] + s[1]) + (s[2] + s[3]);
        }
        __syncthreads();
        float* t = cur; cur = nxt; nxt = t;
    }

    // normalize v10 -> vhat
    float mv = (tid < NC) ? cur[tid] : 0.f;
    float x = mv * mv;
#pragma unroll
    for (int o = 32; o > 0; o >>= 1) x += __shfl_down(x, o, 64);
    if ((tid & 63) == 0) red[tid >> 6] = x;
    __syncthreads();
    float n = red[0];
#pragma unroll
    for (int w = 1; w < 16; w++) n += red[w];
    if (tid < NC) vhat[b * NC + tid] = mv * rsqrtf(n);
}

// ---------------- K3: t[n] = sum_c xb[b][c][n] * vhat[b][c]  (c-split x4) ---
__global__ __launch_bounds__(256)
void k_compute_t(const u16* __restrict__ xb, const float* __restrict__ vhat,
                 float* __restrict__ tp) {
    const int b = blockIdx.z, cc = blockIdx.y, nc = blockIdx.x, tid = threadIdx.x;
    __shared__ float vsh[128];
    if (tid < 128) vsh[tid] = vhat[b * NC + cc * 128 + tid];
    __syncthreads();
    const int n0 = nc * 2048 + tid * 8;
    const u16* xp = xb + (size_t)b * NC * NHW + (size_t)cc * 128 * NHW + n0;
    float acc[8] = {0.f, 0.f, 0.f, 0.f, 0.f, 0.f, 0.f, 0.f};
    for (int c = 0; c < 128; c++) {
        u16x8 w = *(const u16x8*)xp;
        xp += NHW;
        float vc = vsh[c];
#pragma unroll
        for (int j = 0; j < 8; j++) acc[j] += bf2f(w[j]) * vc;
    }
    float* dst = tp + (size_t)(b * 4 + cc) * NHW + n0;
    *(f32x4*)dst       = f32x4{acc[0], acc[1], acc[2], acc[3]};
    *(f32x4*)(dst + 4) = f32x4{acc[4], acc[5], acc[6], acc[7]};
}

// ---------------- K3b: tsum = sum_p tp; sinv = 1/||tsum|| (u-norm) ---------
// s = ||X^T vhat|| = ||t||_2, so no extra matvec is needed for the u-norm.
__global__ __launch_bounds__(1024, 1)
void k_tnorm(const float* __restrict__ tp, float* __restrict__ tsum,
             float* __restrict__ sinv) {
    const int b = blockIdx.x, tid = threadIdx.x;
    __shared__ float red[16];
    const int n0 = tid * 4;  // 1024 threads x 4 = 4096
    f32x4 s = f32x4{0.f, 0.f, 0.f, 0.f};
#pragma unroll
    for (int p = 0; p < 4; p++)
        s += *(const f32x4*)(tp + (size_t)(b * 4 + p) * NHW + n0);
    *(f32x4*)(tsum + (size_t)b * NHW + n0) = s;
    float ss = s[0] * s[0] + s[1] * s[1] + s[2] * s[2] + s[3] * s[3];
#pragma unroll
    for (int o = 32; o > 0; o >>= 1) ss += __shfl_down(ss, o, 64);
    if ((tid & 63) == 0) red[tid >> 6] = ss;
    __syncthreads();
    if (tid == 0) {
        float n = red[0];
#pragma unroll
        for (int w = 1; w < 16; w++) n += red[w];
        sinv[b] = rsqrtf(n);
    }
}

// ---------------- K4: out = x + tsum[n] * (vhat[c] * sinv[b]) ----------------
__global__ __launch_bounds__(256)
void k_epilogue(const float* __restrict__ x, const float* __restrict__ tsum,
                const float* __restrict__ vhat, const float* __restrict__ sinv,
                float* __restrict__ out) {
    const int b = blockIdx.z, cc = blockIdx.y, nc = blockIdx.x, tid = threadIdx.x;
    __shared__ float tl[1024];
    __shared__ float cf[64];
    const int nbase = nc * 1024, cbase = cc * 64;
    const float si = sinv[b];
    for (int i = tid; i < 1024; i += 256)
        tl[i] = tsum[(size_t)b * NHW + nbase + i];
    if (tid < 64) cf[tid] = vhat[b * NC + cbase + tid] * si;
    __syncthreads();
    f32x4 tv = ((const f32x4*)tl)[tid];
    for (int rr = 0; rr < 64; rr++) {
        size_t off = ((size_t)(b * NC + cbase + rr)) * NHW + nbase + tid * 4;
        f32x4 xv = *(const f32x4*)(x + off);
        float c = cf[rr];
        f32x4 o = xv + tv * c;
        *(f32x4*)(out + off) = o;
    }
}

extern "C" void kernel_launch(void* const* d_in, const int* in_sizes, int n_in,
                              void* d_out, int out_size, void* d_ws, size_t ws_size,
                              hipStream_t stream) {
    const float* x  = (const float*)d_in[0];   // (16,512,64,64) fp32
    const float* v0 = (const float*)d_in[1];   // (16,512,1) fp32
    float* out = (float*)d_out;

    char* ws = (char*)d_ws;
    u16* xb     = (u16*)ws;                                   // 64 MiB bf16 x
    u16* S      = (u16*)(ws + 67108864);                      // 8 MiB  Ws/4096
    u16* S2     = (u16*)(ws + 67108864 + 8388608);            // 8 MiB  S^2
    float* vhat = (float*)(ws + 83886080);                    // 32 KiB
    float* tp   = (float*)(ws + 83886080 + 65536);            // 1 MiB (4 c-partials)
    float* tsum = (float*)(ws + 83886080 + 65536 + 1048576);  // 256 KiB
    float* sinv = (float*)(ws + 83886080 + 65536 + 1048576 + 262144);  // 64 B

    k_to_bf16<<<dim3(32768), dim3(256), 0, stream>>>(x, xb);
    // S = (X X^T) / 4096   (M=N=512, K=4096)
    k_gemm_bt<<<dim3(4, 4, NB), dim3(256), 0, stream>>>(
        xb, xb, S, NHW, NC, (size_t)NC * NHW, (size_t)NC * NHW, (size_t)NC * NC,
        1.f / 4096.f);
    // S2 = S * S^T = S * S   (M=N=K=512, S symmetric)
    k_gemm_bt<<<dim3(4, 4, NB), dim3(256), 0, stream>>>(
        S, S, S2, NC, NC, (size_t)NC * NC, (size_t)NC * NC, (size_t)NC * NC, 1.f);
    k_power_iter<<<dim3(NB), dim3(1024), 0, stream>>>(S2, v0, vhat);
    k_compute_t<<<dim3(2, 4, NB), dim3(256), 0, stream>>>(xb, vhat, tp);
    k_tnorm<<<dim3(NB), dim3(1024), 0, stream>>>(tp, tsum, sinv);
    k_epilogue<<<dim3(4, 8, NB), dim3(256), 0, stream>>>(x, tsum, vhat, sinv, out);
}